// Round 5
// baseline (3951.102 us; speedup 1.0000x reference)
//
#include <hip/hip_runtime.h>
#include <hip/hip_cooperative_groups.h>

namespace cg = cooperative_groups;

typedef float f32x4 __attribute__((ext_vector_type(4)));
typedef short s16x8 __attribute__((ext_vector_type(8)));
typedef unsigned short u16;

#define B_    256
#define HW_   196
#define E_    1024
#define H_    1024
#define L_    128
#define T_    48
#define FCOUT 1154   // L + H + 2
#define FCPAD 1216   // next multiple of 64
#define G4H   4096   // 4*H
#define FTILN 19     // FCPAD/64
#define FTILM 192    // B*T/64

__device__ __forceinline__ u16 f2bf(float x) {
  union { float f; unsigned u; } v; v.f = x;
  unsigned r = v.u + 0x7FFF + ((v.u >> 16) & 1);  // RNE
  return (u16)(r >> 16);
}
__device__ __forceinline__ float sigm(float x) { return 1.f / (1.f + expf(-x)); }

// ---------------------------------------------------------------------------
// Setup: strided fp32 -> bf16 convert (with zero row padding for W_fc)
// ---------------------------------------------------------------------------
__global__ __launch_bounds__(256) void cvt_bf16(
    const float* __restrict__ in, u16* __restrict__ out,
    int src_rows, int in_ld, int in_off, int cols, long total) {
  long idx = (long)blockIdx.x * 256 + threadIdx.x;
  if (idx >= total) return;
  int r = (int)(idx / cols);
  int c = (int)(idx % cols);
  float v = (r < src_rows) ? in[(size_t)r * in_ld + in_off + c] : 0.f;
  out[idx] = f2bf(v);
}

// ---------------------------------------------------------------------------
// img_mean[b][e] = mean over HW of image[b][hw][e]; store bf16
// ---------------------------------------------------------------------------
__global__ __launch_bounds__(256) void img_mean_k(
    const float* __restrict__ image, u16* __restrict__ meanB) {
  int idx = blockIdx.x * 256 + threadIdx.x;   // b*1024 + e
  int b = idx >> 10;
  const float* p = image + (size_t)b * HW_ * E_ + (idx & 1023);
  float s = 0.f;
  #pragma unroll 4
  for (int hw = 0; hw < HW_; ++hw) s += p[(size_t)hw * E_];
  meanB[idx] = f2bf(s * (1.0f / HW_));
}

// ---------------------------------------------------------------------------
// Setup NT GEMM (64x64 tile, 4 waves of 32x32 via 2x2 16x16x32 mfma).
// MODE 0: outF = acc + bias1[n] + bias2[n]     (gates_base)
// MODE 1: outB = bf16(tanh(acc + bias1[n]))    (h0)
// MODE 2: outF = tanh(acc + bias1[n])          (m0)
// ---------------------------------------------------------------------------
template <int MODE>
__global__ __launch_bounds__(256) void gemm_nt(
    const u16* __restrict__ A, int lda, const u16* __restrict__ Bp, int ldb, int K,
    const float* __restrict__ bias1, const float* __restrict__ bias2,
    float* __restrict__ outF, u16* __restrict__ outB, int ldc) {
  __shared__ __align__(16) u16 As[64][72];
  __shared__ __align__(16) u16 Bs[64][72];

  const int m0 = blockIdx.x * 64;
  const int n0 = blockIdx.y * 64;
  const int tid  = threadIdx.x;
  const int lane = tid & 63;
  const int wave = tid >> 6;
  const int wm = wave & 1, wn = wave >> 1;
  const int quad = lane >> 4, l16 = lane & 15;
  const int ar = tid >> 3;
  const int ac = (tid & 7) * 8;

  f32x4 acc[2][2] = {};

  for (int kb = 0; kb < K; kb += 64) {
    __syncthreads();
    #pragma unroll
    for (int p = 0; p < 2; ++p) {
      int r = ar + p * 32;
      *(uint4*)&As[r][ac] = *(const uint4*)&A [(size_t)(m0 + r) * lda + kb + ac];
      *(uint4*)&Bs[r][ac] = *(const uint4*)&Bp[(size_t)(n0 + r) * ldb + kb + ac];
    }
    __syncthreads();
    #pragma unroll
    for (int ks = 0; ks < 64; ks += 32) {
      s16x8 a0v = *(const s16x8*)&As[wm * 32      + l16][ks + quad * 8];
      s16x8 a1v = *(const s16x8*)&As[wm * 32 + 16 + l16][ks + quad * 8];
      s16x8 b0v = *(const s16x8*)&Bs[wn * 32      + l16][ks + quad * 8];
      s16x8 b1v = *(const s16x8*)&Bs[wn * 32 + 16 + l16][ks + quad * 8];
      acc[0][0] = __builtin_amdgcn_mfma_f32_16x16x32_bf16(a0v, b0v, acc[0][0], 0, 0, 0);
      acc[0][1] = __builtin_amdgcn_mfma_f32_16x16x32_bf16(a0v, b1v, acc[0][1], 0, 0, 0);
      acc[1][0] = __builtin_amdgcn_mfma_f32_16x16x32_bf16(a1v, b0v, acc[1][0], 0, 0, 0);
      acc[1][1] = __builtin_amdgcn_mfma_f32_16x16x32_bf16(a1v, b1v, acc[1][1], 0, 0, 0);
    }
  }

  #pragma unroll
  for (int mi = 0; mi < 2; ++mi) {
    #pragma unroll
    for (int ni = 0; ni < 2; ++ni) {
      #pragma unroll
      for (int r = 0; r < 4; ++r) {
        int m = m0 + wm * 32 + mi * 16 + quad * 4 + r;
        int n = n0 + wn * 32 + ni * 16 + l16;
        float v = acc[mi][ni][r];
        if constexpr (MODE == 0) {
          outF[(size_t)m * ldc + n] = v + bias1[n] + bias2[n];
        } else if constexpr (MODE == 1) {
          outB[(size_t)m * ldc + n] = f2bf(tanhf(v + bias1[n]));
        } else {
          outF[(size_t)m * ldc + n] = tanhf(v + bias1[n]);
        }
      }
    }
  }
}

// ---------------------------------------------------------------------------
// Persistent cooperative kernel: the whole T=48 scan + batched fc.
// Grid: 256 blocks x 512 threads (1 block/CU, 8 waves).
//
// Scan: block (mb = bid>>5, jb = bid&31) owns the (32 b x 32 j) LSTM state
// tile; m state lives in REGISTERS (2 f32/thread) for all 48 steps.
// gates = gbase + lab_t @ WihL^T + h(t-1) @ Whh^T : 18 k-chunks of 64
// (2 lab + 16 h), double-buffered LDS; wave w computes gate (w&3), b-half
// (w>>2) as a 16x32 frag pair.
//
// Cross-XCD h handoff (the R2 failure): h is stored with AGENT-scope atomic
// stores (sc0/sc1 -> coherence point, not the producer's private L2), fenced,
// then grid.sync(). Each h slot is written exactly once and only read after
// its coherent store, so consumer-side plain vector loads are first-touch
// and fetch correct lines (and later fc re-reads hit correctly-cached data).
//
// fc: after the scan, grid-stride over 192x19 64x64 tiles (same math as R4's
// fc_k), masked scatter into the 4 outputs.
// ---------------------------------------------------------------------------
struct ScanStage { u16 A[2][32][72]; u16 B[2][128][72]; };  // 46080 B
struct FcStage   { u16 A[64][72];    u16 B[64][72]; };      // 18432 B
union StageU { ScanStage s; FcStage f; };

__global__ __launch_bounds__(512, 1) void decoder_k(
    const u16* __restrict__ labB,    // B x T x L
    const u16* __restrict__ WihL,    // 4H x L
    const u16* __restrict__ WhhB,    // 4H x H
    const u16* __restrict__ WfcB,    // FCPAD x H
    const float* __restrict__ gbase, // B x 4H (includes b_ih + b_hh)
    const float* __restrict__ b_fc,  // FCOUT
    u16* __restrict__ hH,            // (T+1) x B x H, slot 0 = h0
    const float* __restrict__ mS,    // B x H f32 (m0)
    const int* __restrict__ length,
    float* __restrict__ out) {
  cg::grid_group grid = cg::this_grid();
  __shared__ StageU st;
  __shared__ float gs[4][32][32];

  const int tid  = threadIdx.x;
  const int lane = tid & 63;
  const int wave = tid >> 6;             // 0..7
  const int quad = lane >> 4, l16 = lane & 15;
  const int g  = wave & 3;               // gate index
  const int bh = wave >> 2;              // b half (0/1)

  const int jb = blockIdx.x & 31;        // j tile (32 wide)
  const int mb = blockIdx.x >> 5;        // b tile (32 wide)

  const int arow = tid >> 3;             // A loader row (tid<256 -> 0..31)
  const int acol = (tid & 7) * 8;
  const int br0  = tid >> 3;             // B loader rows 0..63 / 64..127
  const int br1  = br0 + 64;
  const int wrow0 = (br0 >> 5) * H_ + jb * 32 + (br0 & 31);  // gates 0..1
  const int wrow1 = (br1 >> 5) * H_ + jb * 32 + (br1 & 31);  // gates 2..3

  // update mapping: 2 consecutive j per thread
  const int bl  = tid >> 4;              // 0..31
  const int jl0 = (tid & 15) * 2;        // 0,2,..,30
  const int bg  = mb * 32 + bl;          // global b
  const int jg0 = jb * 32 + jl0;         // global j

  float mreg0 = mS[(size_t)bg * H_ + jg0];
  float mreg1 = mS[(size_t)bg * H_ + jg0 + 1];

  uint4 a_r, b_r0, b_r1;

  // ---------------- the scan ----------------
  for (int t = 0; t < T_; ++t) {
    const u16* hprev = hH + (size_t)t * (B_ * H_);
    u16*       hnext = hH + (size_t)(t + 1) * (B_ * H_);

    auto issue = [&](int i) {
      if (i < 2) {                                  // lab segment, K=128
        int ko = i * 64;
        if (tid < 256)
          a_r = *(const uint4*)&labB[((size_t)(mb * 32 + arow) * T_ + t) * L_ + ko + acol];
        b_r0 = *(const uint4*)&WihL[(size_t)wrow0 * L_ + ko + acol];
        b_r1 = *(const uint4*)&WihL[(size_t)wrow1 * L_ + ko + acol];
      } else {                                      // h segment, K=1024
        int ko = (i - 2) * 64;
        if (tid < 256)
          a_r = *(const uint4*)&hprev[(size_t)(mb * 32 + arow) * H_ + ko + acol];
        b_r0 = *(const uint4*)&WhhB[(size_t)wrow0 * H_ + ko + acol];
        b_r1 = *(const uint4*)&WhhB[(size_t)wrow1 * H_ + ko + acol];
      }
    };
    auto commit = [&](int buf) {
      if (tid < 256) *(uint4*)&st.s.A[buf][arow][acol] = a_r;
      *(uint4*)&st.s.B[buf][br0][acol] = b_r0;
      *(uint4*)&st.s.B[buf][br1][acol] = b_r1;
    };

    f32x4 acc0 = {}, acc1 = {};
    issue(0); commit(0);
    for (int i = 0; i < 18; ++i) {
      if (i + 1 < 18) issue(i + 1);
      __syncthreads();                   // stores to buf[i&1] visible
      const int cur = i & 1;
      #pragma unroll
      for (int ks = 0; ks < 64; ks += 32) {
        s16x8 av  = *(const s16x8*)&st.s.A[cur][bh * 16 + l16][ks + quad * 8];
        s16x8 bv0 = *(const s16x8*)&st.s.B[cur][g * 32      + l16][ks + quad * 8];
        s16x8 bv1 = *(const s16x8*)&st.s.B[cur][g * 32 + 16 + l16][ks + quad * 8];
        acc0 = __builtin_amdgcn_mfma_f32_16x16x32_bf16(av, bv0, acc0, 0, 0, 0);
        acc1 = __builtin_amdgcn_mfma_f32_16x16x32_bf16(av, bv1, acc1, 0, 0, 0);
      }
      __syncthreads();                   // readers done before next commit
      if (i + 1 < 18) commit((i + 1) & 1);
    }

    // gate exchange: wave (g, bh) -> gs[g][b-local][j-local]
    #pragma unroll
    for (int r = 0; r < 4; ++r) {
      gs[g][bh * 16 + quad * 4 + r][l16]      = acc0[r];
      gs[g][bh * 16 + quad * 4 + r][16 + l16] = acc1[r];
    }
    __syncthreads();

    const float* gb = gbase + (size_t)bg * G4H + jg0;
    float gi0 = gs[0][bl][jl0]     + gb[0];
    float gi1 = gs[0][bl][jl0 + 1] + gb[1];
    float gf0 = gs[1][bl][jl0]     + gb[H_];
    float gf1 = gs[1][bl][jl0 + 1] + gb[H_ + 1];
    float gg0 = gs[2][bl][jl0]     + gb[2 * H_];
    float gg1 = gs[2][bl][jl0 + 1] + gb[2 * H_ + 1];
    float go0 = gs[3][bl][jl0]     + gb[3 * H_];
    float go1 = gs[3][bl][jl0 + 1] + gb[3 * H_ + 1];
    mreg0 = sigm(gf0) * mreg0 + sigm(gi0) * tanhf(gg0);
    mreg1 = sigm(gf1) * mreg1 + sigm(gi1) * tanhf(gg1);
    float h0 = sigm(go0) * tanhf(mreg0);
    float h1 = sigm(go1) * tanhf(mreg1);
    unsigned packed = (unsigned)f2bf(h0) | ((unsigned)f2bf(h1) << 16);
    // AGENT-scope coherent store: visible across XCDs after the fence+sync.
    __hip_atomic_store((unsigned*)&hnext[(size_t)bg * H_ + jg0], packed,
                       __ATOMIC_RELAXED, __HIP_MEMORY_SCOPE_AGENT);
    __threadfence();
    grid.sync();
  }

  // ---------------- batched fc, grid-strided ----------------
  const int wm = wave & 1;               // m half (32)
  const int wn = wave >> 1;              // n quarter (16)
  const int frr = tid >> 3;              // 0..63
  const int fcc = (tid & 7) * 8;

  for (int tile = blockIdx.x; tile < FTILM * FTILN; tile += 256) {
    const int m0t = (tile / FTILN) * 64;
    const int n0  = (tile % FTILN) * 64;
    const int tt  = m0t >> 8;            // constant within tile
    const int b0  = m0t & 255;
    const u16* hA = hH + (size_t)(tt + 1) * (B_ * H_);

    f32x4 acc2[2] = {};
    for (int kb = 0; kb < H_; kb += 64) {
      __syncthreads();
      *(uint4*)&st.f.A[frr][fcc] = *(const uint4*)&hA  [(size_t)(b0 + frr) * H_ + kb + fcc];
      *(uint4*)&st.f.B[frr][fcc] = *(const uint4*)&WfcB[(size_t)(n0 + frr) * H_ + kb + fcc];
      __syncthreads();
      #pragma unroll
      for (int ks = 0; ks < 64; ks += 32) {
        s16x8 av0 = *(const s16x8*)&st.f.A[wm * 32      + l16][ks + quad * 8];
        s16x8 av1 = *(const s16x8*)&st.f.A[wm * 32 + 16 + l16][ks + quad * 8];
        s16x8 bv  = *(const s16x8*)&st.f.B[wn * 16      + l16][ks + quad * 8];
        acc2[0] = __builtin_amdgcn_mfma_f32_16x16x32_bf16(av0, bv, acc2[0], 0, 0, 0);
        acc2[1] = __builtin_amdgcn_mfma_f32_16x16x32_bf16(av1, bv, acc2[1], 0, 0, 0);
      }
    }

    #pragma unroll
    for (int mi = 0; mi < 2; ++mi) {
      #pragma unroll
      for (int r = 0; r < 4; ++r) {
        int b = b0 + wm * 32 + mi * 16 + quad * 4 + r;
        int n = n0 + wn * 16 + l16;
        if (n < FCOUT) {
          float rv = fmaxf(acc2[mi][r] + b_fc[n], 0.f);
          float msk = (tt < length[b]) ? 1.f : 0.f;
          if (n < L_) {
            out[(size_t)b * (T_ * L_) + tt * L_ + n] = rv * msk;
          } else if (n < L_ + H_) {
            out[(size_t)(B_ * T_ * L_) + (size_t)b * (T_ * H_) + tt * H_ + (n - L_)] = rv * msk;
          } else if (n == L_ + H_) {
            out[(size_t)B_ * T_ * (L_ + H_) + b * T_ + tt] = expf(rv) * msk;
          } else {
            out[(size_t)B_ * T_ * (L_ + H_ + 1) + b * T_ + tt] = sigm(rv) * msk;
          }
        }
      }
    }
  }
}

// ---------------------------------------------------------------------------
extern "C" void kernel_launch(void* const* d_in, const int* in_sizes, int n_in,
                              void* d_out, int out_size, void* d_ws, size_t ws_size,
                              hipStream_t stream) {
  const float* image  = (const float*)d_in[0];
  const float* label  = (const float*)d_in[1];
  const int*   length = (const int*)  d_in[2];
  const float* W_h    = (const float*)d_in[3];
  const float* b_h    = (const float*)d_in[4];
  const float* W_m    = (const float*)d_in[5];
  const float* b_m    = (const float*)d_in[6];
  const float* W_ih   = (const float*)d_in[7];
  const float* W_hh   = (const float*)d_in[8];
  const float* b_ih   = (const float*)d_in[9];
  const float* b_hh   = (const float*)d_in[10];
  const float* W_fc   = (const float*)d_in[11];
  const float* b_fc   = (const float*)d_in[12];
  float* out = (float*)d_out;

  char* ws = (char*)d_ws;
  size_t off = 0;
  auto alloc = [&](size_t bytes) -> void* {
    void* p = ws + off;
    off = (off + bytes + 255) & ~(size_t)255;
    return p;
  };
  u16*   meanB = (u16*)  alloc((size_t)B_ * E_ * 2);
  u16*   WhB   = (u16*)  alloc((size_t)H_ * E_ * 2);
  u16*   WmB   = (u16*)  alloc((size_t)H_ * E_ * 2);
  u16*   WihE  = (u16*)  alloc((size_t)G4H * E_ * 2);
  u16*   WihL  = (u16*)  alloc((size_t)G4H * L_ * 2);
  u16*   WhhB  = (u16*)  alloc((size_t)G4H * H_ * 2);
  u16*   WfcB  = (u16*)  alloc((size_t)FCPAD * H_ * 2);
  u16*   labB  = (u16*)  alloc((size_t)B_ * T_ * L_ * 2);
  float* gbase = (float*)alloc((size_t)B_ * G4H * 4);
  u16*   hH    = (u16*)  alloc((size_t)(T_ + 1) * B_ * H_ * 2);  // 25.7 MB
  float* mS    = (float*)alloc((size_t)B_ * H_ * 4);

  auto cvt = [&](const float* in, u16* o, int rows, int src_rows, int in_ld,
                 int in_off, int cols) {
    long total = (long)rows * cols;
    int blocks = (int)((total + 255) / 256);
    cvt_bf16<<<blocks, 256, 0, stream>>>(in, o, src_rows, in_ld, in_off, cols, total);
  };

  // --- setup: weight/label conversion to bf16 ---
  cvt(W_h,  WhB,  H_,   H_,   E_,      0,  E_);
  cvt(W_m,  WmB,  H_,   H_,   E_,      0,  E_);
  cvt(W_ih, WihE, G4H,  G4H,  E_ + L_, 0,  E_);   // columns [0, E)
  cvt(W_ih, WihL, G4H,  G4H,  E_ + L_, E_, L_);   // columns [E, E+L)
  cvt(W_hh, WhhB, G4H,  G4H,  H_,      0,  H_);
  cvt(W_fc, WfcB, FCPAD, FCOUT, H_,    0,  H_);   // zero-padded rows
  cvt(label, labB, B_, B_, T_ * L_, 0, T_ * L_);

  img_mean_k<<<(B_ * E_) / 256, 256, 0, stream>>>(image, meanB);

  // --- setup GEMMs ---
  // h0 = tanh(mean @ W_h^T + b_h) -> bf16 into hH slot 0
  gemm_nt<1><<<dim3(B_ / 64, H_ / 64), 256, 0, stream>>>(
      meanB, E_, WhB, E_, E_, b_h, nullptr, nullptr, hH, H_);
  // m0 = tanh(mean @ W_m^T + b_m) -> f32
  gemm_nt<2><<<dim3(B_ / 64, H_ / 64), 256, 0, stream>>>(
      meanB, E_, WmB, E_, E_, b_m, nullptr, mS, nullptr, H_);
  // gates_base = mean @ W_ihE^T + b_ih + b_hh -> f32
  gemm_nt<0><<<dim3(B_ / 64, G4H / 64), 256, 0, stream>>>(
      meanB, E_, WihE, E_, E_, b_ih, b_hh, gbase, nullptr, G4H);

  // --- whole scan + batched fc in ONE cooperative kernel ---
  void* kargs[] = {
      (void*)&labB, (void*)&WihL, (void*)&WhhB, (void*)&WfcB,
      (void*)&gbase, (void*)&b_fc, (void*)&hH, (void*)&mS,
      (void*)&length, (void*)&out};
  hipLaunchCooperativeKernel((void*)decoder_k, dim3(256), dim3(512), kargs, 0, stream);
}